// Round 4
// baseline (10836.396 us; speedup 1.0000x reference)
//
#include <hip/hip_runtime.h>
#include <cstdint>
#include <cstddef>

typedef __attribute__((ext_vector_type(4))) int int32x4;
typedef __attribute__((ext_vector_type(16))) int int32x16;

#define DEVI __device__ __forceinline__

constexpr int M = 16384;
constexpr int N = 11008;
constexpr int K = 4096;
constexpr int BM = 256, BN = 256, BK = 32;   // BK in int8 elements (= bytes)
constexpr int NT_M = M / BM;                 // 64
constexpr int NT_N = N / BN;                 // 43
constexpr int NTILES = K / BK;               // 128
constexpr int NWG = NT_M * NT_N;             // 2752 = 8 * 344 (exact)
constexpr int SLOT = 16384;                  // 8 KB A + 8 KB B per ring slot

DEVI void gload_lds16(const void* gsrc, void* ldst) {
  __builtin_amdgcn_global_load_lds(
      (const __attribute__((address_space(1))) unsigned int*)gsrc,
      (__attribute__((address_space(3))) unsigned int*)ldst,
      16, 0, 0);
}

// ---- weight repack: int32 (harness int convention) -> int8 ----
__global__ __launch_bounds__(256) void pack_w_kernel(const int* __restrict__ w32,
                                                     signed char* __restrict__ w8) {
  const int idx = blockIdx.x * 256 + threadIdx.x;
  const int total4 = N * K / 4;
  if (idx < total4) {
    const int4 v = ((const int4*)w32)[idx];
    ((int*)w8)[idx] = (v.x & 255) | ((v.y & 255) << 8) |
                      ((v.z & 255) << 16) | ((v.w & 255) << 24);
  }
}

// ---- per-row symmetric int8 quantization of X ----
__global__ __launch_bounds__(256) void quant_x_kernel(const float* __restrict__ x,
                                                      signed char* __restrict__ xq,
                                                      float* __restrict__ sx) {
  const int row = blockIdx.x;
  const int t = threadIdx.x;
  const float4* xr = (const float4*)(x + (size_t)row * K);
  float4 v[4];
  float amax = 0.f;
  #pragma unroll
  for (int c = 0; c < 4; ++c) {
    v[c] = xr[c * 256 + t];
    amax = fmaxf(amax, fmaxf(fmaxf(fabsf(v[c].x), fabsf(v[c].y)),
                             fmaxf(fabsf(v[c].z), fabsf(v[c].w))));
  }
  __shared__ float red[256];
  red[t] = amax;
  __syncthreads();
  #pragma unroll
  for (int s = 128; s >= 1; s >>= 1) {
    if (t < s) red[t] = fmaxf(red[t], red[t + s]);
    __syncthreads();
  }
  const float am = fmaxf(red[0], 1e-20f);
  const float inv = 127.f / am;
  if (t == 0) sx[row] = am * (1.f / 127.f);
  int* xq32 = (int*)(xq + (size_t)row * K);
  #pragma unroll
  for (int c = 0; c < 4; ++c) {
    int q0 = min(127, max(-127, __float2int_rn(v[c].x * inv)));
    int q1 = min(127, max(-127, __float2int_rn(v[c].y * inv)));
    int q2 = min(127, max(-127, __float2int_rn(v[c].z * inv)));
    int q3 = min(127, max(-127, __float2int_rn(v[c].w * inv)));
    xq32[c * 256 + t] = (q0 & 255) | ((q1 & 255) << 8) |
                        ((q2 & 255) << 16) | ((q3 & 255) << 24);
  }
}

// ---- 256x256 int8 GEMM, BK=32, ring-4 LDS (64 KiB -> 2 blocks/CU) ----
// 4 waves, each owns a 128x128 output tile (4x4 frags of 32x32).
// LDS per slot: A 8 KB (k-plane-major: plane*4096 + row*16) then B 8 KB.
// Staging: thread t stages A[m0+t][kt*32 + {0,16}] and B rows likewise;
// dest = chunk*16 is exactly linear (plane-major falls out of chunk id).
// Counted vmcnt: stage t+3 each iter; wait vmcnt(8) BEFORE the barrier
// (each wave certifies its own tile-t loads; barrier publishes all).
__global__ __launch_bounds__(256, 2) void gemm_i8_kernel(const signed char* __restrict__ aq,
                                                         const signed char* __restrict__ wq,
                                                         const float* __restrict__ sx,
                                                         const float* __restrict__ sw,
                                                         float* __restrict__ out) {
  __shared__ __align__(16) signed char smem[4 * SLOT];   // 64 KiB

  const int t = threadIdx.x;       // 0..255
  const int w = t >> 6;            // wave 0..3
  const int l = t & 63;

  // XCD-aware swizzle (bijective: 2752 % 8 == 0).
  const int bid = blockIdx.x;
  const int wg = (bid & 7) * (NWG / 8) + (bid >> 3);
  const int mt = wg / NT_N;
  const int nt = wg % NT_N;
  const int m0 = mt * BM, n0 = nt * BN;

  // Staging sources: one A row + one B row per thread.
  const signed char* aRow = aq + (size_t)(m0 + t) * K;
  const signed char* bRow = wq + (size_t)(n0 + t) * K;
  // LDS dest (wave-uniform base; HW adds lane*16): chunk q dest = q*16.
  const int dA0 = w * 1024;              // plane 0 (cols 0..15 of the 32B step)
  const int dA1 = w * 1024 + 4096;       // plane 1 (cols 16..31)

#define STAGE(tile)                                                           \
  {                                                                           \
    signed char* sb = smem + ((tile) & 3) * SLOT;                             \
    const int ko = (tile) * BK;                                               \
    gload_lds16(aRow + ko,      sb + dA0);                                    \
    gload_lds16(aRow + ko + 16, sb + dA1);                                    \
    gload_lds16(bRow + ko,      sb + 8192 + dA0);                             \
    gload_lds16(bRow + ko + 16, sb + 8192 + dA1);                             \
  }

  // Wave output: 128x128 at (wm*128, wn*128); 4x4 frags of 32x32.
  const int wm = w >> 1, wn = w & 1;
  const int lk = l >> 5;           // k-plane 0/1
  const int lr = l & 31;
  int aOff[4], bOff[4];
  #pragma unroll
  for (int i = 0; i < 4; ++i)
    aOff[i] = lk * 4096 + (wm * 128 + i * 32 + lr) * 16;
  #pragma unroll
  for (int j = 0; j < 4; ++j)
    bOff[j] = 8192 + lk * 4096 + (wn * 128 + j * 32 + lr) * 16;

  int32x16 acc[4][4] = {};
  int32x4 af[4], bf[4];

#define DS_LOADS(tile)                                                        \
  {                                                                           \
    const signed char* sb = smem + ((tile) & 3) * SLOT;                       \
    af[0] = *(const int32x4*)(sb + aOff[0]);                                  \
    af[1] = *(const int32x4*)(sb + aOff[1]);                                  \
    af[2] = *(const int32x4*)(sb + aOff[2]);                                  \
    af[3] = *(const int32x4*)(sb + aOff[3]);                                  \
    bf[0] = *(const int32x4*)(sb + bOff[0]);                                  \
    bf[1] = *(const int32x4*)(sb + bOff[1]);                                  \
    bf[2] = *(const int32x4*)(sb + bOff[2]);                                  \
    bf[3] = *(const int32x4*)(sb + bOff[3]);                                  \
  }

#define LGKM0()                                          \
  asm volatile("s_waitcnt lgkmcnt(0)" ::: "memory");     \
  __builtin_amdgcn_sched_barrier(0);

#define MFMA16()                                                              \
  __builtin_amdgcn_s_setprio(1);                                              \
  {                                                                           \
    _Pragma("unroll")                                                         \
    for (int i = 0; i < 4; ++i) {                                             \
      _Pragma("unroll")                                                       \
      for (int j = 0; j < 4; ++j) {                                           \
        acc[i][j] = __builtin_amdgcn_mfma_i32_32x32x32_i8(af[i], bf[j],       \
                                                          acc[i][j], 0, 0, 0);\
      }                                                                       \
    }                                                                         \
  }                                                                           \
  __builtin_amdgcn_s_setprio(0);

#define WAITV(n) asm volatile("s_waitcnt vmcnt(" #n ")" ::: "memory");
#define BAR() __builtin_amdgcn_s_barrier();

  // Prologue: stage tiles 0..2 (12 loads in flight).
  STAGE(0) STAGE(1) STAGE(2)

  #pragma unroll 4
  for (int tt = 0; tt < 124; ++tt) {
    WAITV(8)            // own tile-tt loads landed (12 - 4 retired -> 8 left)
    BAR()               // publishes all waves' tile-tt data
    STAGE(tt + 3)       // overwrites buf[(tt-1)&3] — reads of tt-1 retired pre-BAR
    DS_LOADS(tt)
    LGKM0()
    MFMA16()
  }
  // tt = 124: last staging tile (127)
  WAITV(8) BAR() STAGE(127) DS_LOADS(124) LGKM0() MFMA16()
  // tt = 125: tiles 126,127 in flight
  WAITV(8) BAR() DS_LOADS(125) LGKM0() MFMA16()
  // tt = 126: tile 127 in flight
  WAITV(4) BAR() DS_LOADS(126) LGKM0() MFMA16()
  // tt = 127
  WAITV(0) BAR() DS_LOADS(127) LGKM0() MFMA16()

  // Epilogue: dequant + store.
  // 32x32 C/D map: col = lane&31, row = (r&3) + 8*(r>>2) + 4*(lane>>5).
  const int rbase = lk * 4;
  float swv[4];
  #pragma unroll
  for (int j = 0; j < 4; ++j) swv[j] = sw[n0 + wn * 128 + j * 32 + lr];
  #pragma unroll
  for (int i = 0; i < 4; ++i) {
    #pragma unroll
    for (int r = 0; r < 16; ++r) {
      const int row = (r & 3) + 8 * (r >> 2) + rbase;
      const int grow = m0 + wm * 128 + i * 32 + row;
      const float sxv = sx[grow];
      float* orow = out + (size_t)grow * N + n0 + wn * 128 + lr;
      #pragma unroll
      for (int j = 0; j < 4; ++j) {
        orow[j * 32] = (float)acc[i][j][r] * sxv * swv[j];
      }
    }
  }
}

extern "C" void kernel_launch(void* const* d_in, const int* in_sizes, int n_in,
                              void* d_out, int out_size, void* d_ws, size_t ws_size,
                              hipStream_t stream) {
  const float* x = (const float*)d_in[0];
  const int* w32 = (const int*)d_in[1];
  const float* wscale = (const float*)d_in[2];
  float* out = (float*)d_out;

  signed char* xq = (signed char*)d_ws;
  signed char* wq = xq + (size_t)M * K;
  float* sx = (float*)(wq + (size_t)N * K);

  pack_w_kernel<<<(N * K / 4 + 255) / 256, 256, 0, stream>>>(w32, wq);
  quant_x_kernel<<<M, 256, 0, stream>>>(x, xq, sx);
  gemm_i8_kernel<<<NWG, 256, 0, stream>>>(xq, wq, sx, wscale, out);
}

// Round 5
// 1622.371 us; speedup vs baseline: 6.6794x; 6.6794x over previous
//
#include <hip/hip_runtime.h>
#include <cstdint>
#include <cstddef>

typedef __attribute__((ext_vector_type(4))) int int32x4;
typedef __attribute__((ext_vector_type(16))) int int32x16;

#define DEVI __device__ __forceinline__

constexpr int M = 16384;
constexpr int N = 11008;
constexpr int K = 4096;
constexpr int BM = 256, BN = 256, BK = 32;   // BK in int8 elements (= bytes)
constexpr int NT_M = M / BM;                 // 64
constexpr int NT_N = N / BN;                 // 43
constexpr int NTILES = K / BK;               // 128
constexpr int NWG = NT_M * NT_N;             // 2752 = 8 * 344 (exact)
constexpr int SLOT = 16384;                  // 8 KB A + 8 KB B per ring slot

DEVI void gload_lds16(const void* gsrc, void* ldst) {
  __builtin_amdgcn_global_load_lds(
      (const __attribute__((address_space(1))) unsigned int*)gsrc,
      (__attribute__((address_space(3))) unsigned int*)ldst,
      16, 0, 0);
}

// ---- weight repack: int32 (harness int convention) -> int8 ----
__global__ __launch_bounds__(256) void pack_w_kernel(const int* __restrict__ w32,
                                                     signed char* __restrict__ w8) {
  const int idx = blockIdx.x * 256 + threadIdx.x;
  const int total4 = N * K / 4;
  if (idx < total4) {
    const int4 v = ((const int4*)w32)[idx];
    ((int*)w8)[idx] = (v.x & 255) | ((v.y & 255) << 8) |
                      ((v.z & 255) << 16) | ((v.w & 255) << 24);
  }
}

// ---- per-row symmetric int8 quantization of X ----
__global__ __launch_bounds__(256) void quant_x_kernel(const float* __restrict__ x,
                                                      signed char* __restrict__ xq,
                                                      float* __restrict__ sx) {
  const int row = blockIdx.x;
  const int t = threadIdx.x;
  const float4* xr = (const float4*)(x + (size_t)row * K);
  float4 v[4];
  float amax = 0.f;
  #pragma unroll
  for (int c = 0; c < 4; ++c) {
    v[c] = xr[c * 256 + t];
    amax = fmaxf(amax, fmaxf(fmaxf(fabsf(v[c].x), fabsf(v[c].y)),
                             fmaxf(fabsf(v[c].z), fabsf(v[c].w))));
  }
  __shared__ float red[256];
  red[t] = amax;
  __syncthreads();
  #pragma unroll
  for (int s = 128; s >= 1; s >>= 1) {
    if (t < s) red[t] = fmaxf(red[t], red[t + s]);
    __syncthreads();
  }
  const float am = fmaxf(red[0], 1e-20f);
  const float inv = 127.f / am;
  if (t == 0) sx[row] = am * (1.f / 127.f);
  int* xq32 = (int*)(xq + (size_t)row * K);
  #pragma unroll
  for (int c = 0; c < 4; ++c) {
    int q0 = min(127, max(-127, __float2int_rn(v[c].x * inv)));
    int q1 = min(127, max(-127, __float2int_rn(v[c].y * inv)));
    int q2 = min(127, max(-127, __float2int_rn(v[c].z * inv)));
    int q3 = min(127, max(-127, __float2int_rn(v[c].w * inv)));
    xq32[c * 256 + t] = (q0 & 255) | ((q1 & 255) << 8) |
                        ((q2 & 255) << 16) | ((q3 & 255) << 24);
  }
}

// ---- 256x256 int8 GEMM, BK=32, ring-4 LDS (64 KiB), reg double-buffer ----
// 8 waves (512 thr), wave tile 128x64 (4x2 frags of 32x32, acc = 128 regs).
// Per iter t: waitv(2); s_barrier (publishes tile t+1); ds_read tile t+1's
// 6 frags into ALTERNATE reg set; stage tile t+3 (2 gload_lds); lgkmcnt(6)
// (tile t's frags done, t+1's in flight); MFMA(t) x8 — t+1's LDS traffic
// hides under the 586-cyc MFMA cluster. One barrier per tile.
// LDS slot: A 8 KB k-plane-major (plane*4096 + row*16), B 8 KB at +8192.
// Staging: thread t stages A[m0 + (t&255)][kt*32 + (t>>8)*16], linear dest.
__global__ __launch_bounds__(512, 2) void gemm_i8_kernel(const signed char* __restrict__ aq,
                                                         const signed char* __restrict__ wq,
                                                         const float* __restrict__ sx,
                                                         const float* __restrict__ sw,
                                                         float* __restrict__ out) {
  __shared__ __align__(16) signed char smem[4 * SLOT];   // 64 KiB

  const int t = threadIdx.x;       // 0..511
  const int w = t >> 6;            // wave 0..7
  const int l = t & 63;

  // XCD-aware swizzle (bijective: 2752 % 8 == 0).
  const int bid = blockIdx.x;
  const int wg = (bid & 7) * (NWG / 8) + (bid >> 3);
  const int mt = wg / NT_N;
  const int nt = wg % NT_N;
  const int m0 = mt * BM, n0 = nt * BN;

  // Staging: one A chunk + one B chunk (16 B) per thread per tile.
  const signed char* aRow = aq + (size_t)(m0 + (t & 255)) * K + (t >> 8) * 16;
  const signed char* bRow = wq + (size_t)(n0 + (t & 255)) * K + (t >> 8) * 16;
  const int dOff = w * 1024;       // wave-uniform dest base; HW adds lane*16

#define STAGE(tile)                                                           \
  {                                                                           \
    signed char* sb = smem + ((tile) & 3) * SLOT;                             \
    const int ko = (tile) * BK;                                               \
    gload_lds16(aRow + ko, sb + dOff);                                        \
    gload_lds16(bRow + ko, sb + 8192 + dOff);                                 \
  }

  // Wave output: 128x64 at (wm*128, wn*64); 4x2 frags of 32x32.
  const int wm = w >> 2, wn = w & 3;
  const int lk = l >> 5;           // k-plane 0/1
  const int lr = l & 31;
  int aOff[4], bOff[2];
  #pragma unroll
  for (int i = 0; i < 4; ++i)
    aOff[i] = lk * 4096 + (wm * 128 + i * 32 + lr) * 16;
  #pragma unroll
  for (int j = 0; j < 2; ++j)
    bOff[j] = 8192 + lk * 4096 + (wn * 64 + j * 32 + lr) * 16;

  int32x16 acc[4][2] = {};
  int32x4 af0[4], bf0[2], af1[4], bf1[2];

#define DSL(tile, af, bf)                                                     \
  {                                                                           \
    const signed char* sb = smem + ((tile) & 3) * SLOT;                       \
    af[0] = *(const int32x4*)(sb + aOff[0]);                                  \
    af[1] = *(const int32x4*)(sb + aOff[1]);                                  \
    af[2] = *(const int32x4*)(sb + aOff[2]);                                  \
    af[3] = *(const int32x4*)(sb + aOff[3]);                                  \
    bf[0] = *(const int32x4*)(sb + bOff[0]);                                  \
    bf[1] = *(const int32x4*)(sb + bOff[1]);                                  \
  }

#define MFMA8(af, bf)                                                         \
  __builtin_amdgcn_s_setprio(1);                                              \
  {                                                                           \
    _Pragma("unroll")                                                         \
    for (int i = 0; i < 4; ++i) {                                             \
      acc[i][0] = __builtin_amdgcn_mfma_i32_32x32x32_i8(af[i], bf[0],         \
                                                        acc[i][0], 0, 0, 0);  \
      acc[i][1] = __builtin_amdgcn_mfma_i32_32x32x32_i8(af[i], bf[1],         \
                                                        acc[i][1], 0, 0, 0);  \
    }                                                                         \
  }                                                                           \
  __builtin_amdgcn_s_setprio(0);

#define WAITV(n) asm volatile("s_waitcnt vmcnt(" #n ")" ::: "memory");
#define WLGKM(n)                                                              \
  asm volatile("s_waitcnt lgkmcnt(" #n ")" ::: "memory");                     \
  __builtin_amdgcn_sched_barrier(0);
#define BAR() __builtin_amdgcn_s_barrier();

#define ITER(tt, AC, BC, AN, BN_)                                             \
  WAITV(2)                  /* own tile-(tt+1) stage landed */                 \
  BAR()                     /* all waves' tile-(tt+1) published */             \
  DSL(tt + 1, AN, BN_)      /* reads overlap MFMA below */                    \
  STAGE(tt + 3)             /* overwrites slot (tt-1): reads done pre-BAR */  \
  WLGKM(6)                  /* tile-tt frags complete; 6 new still in flight */\
  MFMA8(AC, BC)

  // Prologue: stage tiles 0..2 (6 loads); tile 0 landed -> read its frags.
  STAGE(0) STAGE(1) STAGE(2)
  WAITV(4)
  BAR()
  DSL(0, af0, bf0)

  for (int tb = 0; tb < 124; tb += 4) {
    ITER(tb + 0, af0, bf0, af1, bf1)
    ITER(tb + 1, af1, bf1, af0, bf0)
    ITER(tb + 2, af0, bf0, af1, bf1)
    ITER(tb + 3, af1, bf1, af0, bf0)
  }
  // tt = 124 (stages tile 127, the last)
  ITER(124, af0, bf0, af1, bf1)
  // tt = 125
  WAITV(2) BAR() DSL(126, af0, bf0) WLGKM(6) MFMA8(af1, bf1)
  // tt = 126
  WAITV(0) BAR() DSL(127, af1, bf1) WLGKM(6) MFMA8(af0, bf0)
  // tt = 127
  WLGKM(0) MFMA8(af1, bf1)

  // Epilogue: dequant + store.
  // 32x32 C/D map: col = lane&31, row = (r&3) + 8*(r>>2) + 4*(lane>>5).
  const int rbase = lk * 4;
  float swv[2];
  #pragma unroll
  for (int fj = 0; fj < 2; ++fj) swv[fj] = sw[n0 + wn * 64 + fj * 32 + lr];
  #pragma unroll
  for (int fi = 0; fi < 4; ++fi) {
    #pragma unroll
    for (int r = 0; r < 16; ++r) {
      const int row = (r & 3) + 8 * (r >> 2) + rbase;
      const int grow = m0 + wm * 128 + fi * 32 + row;
      const float sxv = sx[grow];
      float* orow = out + (size_t)grow * N + n0 + wn * 64 + lr;
      #pragma unroll
      for (int fj = 0; fj < 2; ++fj) {
        orow[fj * 32] = (float)acc[fi][fj][r] * sxv * swv[fj];
      }
    }
  }
}

extern "C" void kernel_launch(void* const* d_in, const int* in_sizes, int n_in,
                              void* d_out, int out_size, void* d_ws, size_t ws_size,
                              hipStream_t stream) {
  const float* x = (const float*)d_in[0];
  const int* w32 = (const int*)d_in[1];
  const float* wscale = (const float*)d_in[2];
  float* out = (float*)d_out;

  signed char* xq = (signed char*)d_ws;
  signed char* wq = xq + (size_t)M * K;
  float* sx = (float*)(wq + (size_t)N * K);

  pack_w_kernel<<<(N * K / 4 + 255) / 256, 256, 0, stream>>>(w32, wq);
  quant_x_kernel<<<M, 256, 0, stream>>>(x, xq, sx);
  gemm_i8_kernel<<<NWG, 512, 0, stream>>>(xq, wq, sx, wscale, out);
}

// Round 6
// 1033.195 us; speedup vs baseline: 10.4882x; 1.5702x over previous
//
#include <hip/hip_runtime.h>
#include <cstdint>
#include <cstddef>

typedef __attribute__((ext_vector_type(4))) int int32x4;
typedef __attribute__((ext_vector_type(16))) int int32x16;

#define DEVI __device__ __forceinline__

constexpr int M = 16384;
constexpr int N = 11008;
constexpr int K = 4096;
constexpr int BM = 256, BN = 256, BK = 64;   // BK in int8 elements (= bytes)
constexpr int NT_M = M / BM;                 // 64
constexpr int NT_N = N / BN;                 // 43
constexpr int NTILES = K / BK;               // 64
constexpr int NWG = NT_M * NT_N;             // 2752 = 8 * 344 (exact)
constexpr int TILE_BYTES = BM * BK;          // 16 KB per tensor per slot

DEVI void gload_lds16(const void* gsrc, void* ldst) {
  __builtin_amdgcn_global_load_lds(
      (const __attribute__((address_space(1))) unsigned int*)gsrc,
      (__attribute__((address_space(3))) unsigned int*)ldst,
      16, 0, 0);
}

// ---- weight repack: int32 (harness int convention) -> int8 ----
__global__ __launch_bounds__(256) void pack_w_kernel(const int* __restrict__ w32,
                                                     signed char* __restrict__ w8) {
  const int idx = blockIdx.x * 256 + threadIdx.x;
  const int total4 = N * K / 4;
  if (idx < total4) {
    const int4 v = ((const int4*)w32)[idx];
    ((int*)w8)[idx] = (v.x & 255) | ((v.y & 255) << 8) |
                      ((v.z & 255) << 16) | ((v.w & 255) << 24);
  }
}

// ---- per-row symmetric int8 quantization of X ----
__global__ __launch_bounds__(256) void quant_x_kernel(const float* __restrict__ x,
                                                      signed char* __restrict__ xq,
                                                      float* __restrict__ sx) {
  const int row = blockIdx.x;
  const int t = threadIdx.x;
  const float4* xr = (const float4*)(x + (size_t)row * K);
  float4 v[4];
  float amax = 0.f;
  #pragma unroll
  for (int c = 0; c < 4; ++c) {
    v[c] = xr[c * 256 + t];
    amax = fmaxf(amax, fmaxf(fmaxf(fabsf(v[c].x), fabsf(v[c].y)),
                             fmaxf(fabsf(v[c].z), fabsf(v[c].w))));
  }
  __shared__ float red[256];
  red[t] = amax;
  __syncthreads();
  #pragma unroll
  for (int s = 128; s >= 1; s >>= 1) {
    if (t < s) red[t] = fmaxf(red[t], red[t + s]);
    __syncthreads();
  }
  const float am = fmaxf(red[0], 1e-20f);
  const float inv = 127.f / am;
  if (t == 0) sx[row] = am * (1.f / 127.f);
  int* xq32 = (int*)(xq + (size_t)row * K);
  #pragma unroll
  for (int c = 0; c < 4; ++c) {
    int q0 = min(127, max(-127, __float2int_rn(v[c].x * inv)));
    int q1 = min(127, max(-127, __float2int_rn(v[c].y * inv)));
    int q2 = min(127, max(-127, __float2int_rn(v[c].z * inv)));
    int q3 = min(127, max(-127, __float2int_rn(v[c].w * inv)));
    xq32[c * 256 + t] = (q0 & 255) | ((q1 & 255) << 8) |
                        ((q2 & 255) << 16) | ((q3 & 255) << 24);
  }
}

// ---- 256x256 int8 GEMM, BK=64, ring-4 LDS (128 KiB), reg double-buffer ----
// 8 waves, wave tile 128x64 (4x2 frags of 32x32, acc = 128 AGPR).
// Two frag sets (6 x b128 each). Substep stream: tile t sub0 -> sub1.
// Per iter t: WAITV(4) [tile t+1 landed; issued 2 long iters ago ~3400cyc >
// HBM 900cyc]; BAR [publish]; STAGE(t+3); DSL(t,sub1)->set1; lgkm(6) [sub0
// done, sub1 in flight]; MFMA(set0); DSL(t+1,sub0)->set0; lgkm(6); MFMA(set1).
// LDS reads (~1150 cyc/CU/tile) hide under MFMA clusters (~1170 cyc/SIMD).
// LDS slot: A 16 KB k-plane-major (plane*4096 + row*16), B 16 KB at +16384.
__global__ __launch_bounds__(512, 2) void gemm_i8_kernel(const signed char* __restrict__ aq,
                                                         const signed char* __restrict__ wq,
                                                         const float* __restrict__ sx,
                                                         const float* __restrict__ sw,
                                                         float* __restrict__ out) {
  extern __shared__ signed char smem[];            // 131072 B: 4 slots x 32 KB
  signed char* lsA = smem;                          // per slot: A at +0
  signed char* lsB = smem + 4 * TILE_BYTES;         // B region (4 slots x 16 KB)

  const int t = threadIdx.x;
  const int w = t >> 6;            // wave 0..7
  const int l = t & 63;

  // XCD-aware swizzle (bijective: 2752 % 8 == 0).
  const int bid = blockIdx.x;
  const int wg = (bid & 7) * (NWG / 8) + (bid >> 3);
  const int mt = wg / NT_N;
  const int nt = wg % NT_N;
  const int m0 = mt * BM, n0 = nt * BN;

  // Staging: waves 0..3 stage A, waves 4..7 stage B; 4 x 16B chunks/thread.
  const bool stA = (w < 4);
  const signed char* src[4];
  int loff[4];
  #pragma unroll
  for (int c = 0; c < 4; ++c) {
    const int q = (w & 3) * 4 + c;       // chunk id within this tensor
    const int row = (q & 3) * 64 + l;
    const int s = q >> 2;                // k-plane
    const signed char* base = stA ? (aq + (size_t)(m0 + row) * K)
                                  : (wq + (size_t)(n0 + row) * K);
    src[c] = base + s * 16;
    loff[c] = q * 1024;                  // wave-uniform dest; HW adds lane*16
  }

#define STAGE(tile)                                                           \
  {                                                                           \
    signed char* lbase = (stA ? lsA : lsB) + ((tile) & 3) * TILE_BYTES;       \
    const int koff = (tile) * BK;                                             \
    gload_lds16(src[0] + koff, lbase + loff[0]);                              \
    gload_lds16(src[1] + koff, lbase + loff[1]);                              \
    gload_lds16(src[2] + koff, lbase + loff[2]);                              \
    gload_lds16(src[3] + koff, lbase + loff[3]);                              \
  }

  // Wave output: 128x64 at (wm*128, wn*64); 4x2 frags of 32x32.
  const int wm = w >> 2, wn = w & 3;
  const int lk = l >> 5;           // k-chunk within substep (2 x 16B planes)
  const int lr = l & 31;
  int aOff[4], bOff[2];
  #pragma unroll
  for (int i = 0; i < 4; ++i)
    aOff[i] = lk * 4096 + (wm * 128 + i * 32 + lr) * 16;
  #pragma unroll
  for (int j = 0; j < 2; ++j)
    bOff[j] = lk * 4096 + (wn * 64 + j * 32 + lr) * 16;

  int32x16 acc[4][2] = {};
  int32x4 af0[4], bf0[2], af1[4], bf1[2];

  // DSL(tile, sub): 6 ds_read_b128 into the named set. sub selects planes
  // {0,1} (ko=0) or {2,3} (ko=8192).
#define DSL(tile, sub, AF, BF)                                                \
  {                                                                           \
    const signed char* pA = lsA + ((tile) & 3) * TILE_BYTES + (sub) * 8192;   \
    const signed char* pB = lsB + ((tile) & 3) * TILE_BYTES + (sub) * 8192;   \
    AF[0] = *(const int32x4*)(pA + aOff[0]);                                  \
    AF[1] = *(const int32x4*)(pA + aOff[1]);                                  \
    AF[2] = *(const int32x4*)(pA + aOff[2]);                                  \
    AF[3] = *(const int32x4*)(pA + aOff[3]);                                  \
    BF[0] = *(const int32x4*)(pB + bOff[0]);                                  \
    BF[1] = *(const int32x4*)(pB + bOff[1]);                                  \
  }

#define MFMA8(AF, BF)                                                         \
  __builtin_amdgcn_s_setprio(1);                                              \
  {                                                                           \
    _Pragma("unroll")                                                         \
    for (int i = 0; i < 4; ++i) {                                             \
      acc[i][0] = __builtin_amdgcn_mfma_i32_32x32x32_i8(AF[i], BF[0],         \
                                                        acc[i][0], 0, 0, 0);  \
      acc[i][1] = __builtin_amdgcn_mfma_i32_32x32x32_i8(AF[i], BF[1],         \
                                                        acc[i][1], 0, 0, 0);  \
    }                                                                         \
  }                                                                           \
  __builtin_amdgcn_s_setprio(0);

#define WAITV(n) asm volatile("s_waitcnt vmcnt(" #n ")" ::: "memory");
#define WLGKM(n)                                                              \
  asm volatile("s_waitcnt lgkmcnt(" #n ")" ::: "memory");                     \
  __builtin_amdgcn_sched_barrier(0);
#define BAR() __builtin_amdgcn_s_barrier();

  // Steady-state iteration. On entry: Read(t.sub0) in flight or done (set0);
  // tiles t+1, t+2 staged (8 vm loads outstanding).
#define ITER(tt)                                                              \
  WAITV(4)                  /* tile tt+1 landed (tt+2 still in flight) */      \
  BAR()                     /* publish tt+1; tt-1 reads all retired */         \
  STAGE(tt + 3)             /* overwrites slot (tt-1)&3 — safe after BAR */   \
  DSL(tt, 1, af1, bf1)      /* Read(tt.1) -> set1, overlaps MFMA below */     \
  WLGKM(6)                  /* Read(tt.0) complete */                          \
  MFMA8(af0, bf0)           /* tile tt sub0 */                                 \
  DSL(tt + 1, 0, af0, bf0)  /* Read(tt+1.0) -> set0 (tt+1 certified above) */ \
  WLGKM(6)                  /* Read(tt.1) complete */                          \
  MFMA8(af1, bf1)           /* tile tt sub1 */

  // Prologue: stage tiles 0..2 (12 loads); tile 0 landed -> read sub0.
  STAGE(0) STAGE(1) STAGE(2)
  WAITV(8)
  BAR()
  DSL(0, 0, af0, bf0)

  #pragma unroll 4
  for (int tb = 0; tb < 60; ++tb) {
    ITER(tb)
  }
  ITER(60)   // stages tile 63 (last)
  // tt = 61: tiles 62,63 outstanding (8) -> wait 62 done
  WAITV(4) BAR()
  DSL(61, 1, af1, bf1) WLGKM(6) MFMA8(af0, bf0)
  DSL(62, 0, af0, bf0) WLGKM(6) MFMA8(af1, bf1)
  // tt = 62: wait tile 63 done
  WAITV(0) BAR()
  DSL(62, 1, af1, bf1) WLGKM(6) MFMA8(af0, bf0)
  DSL(63, 0, af0, bf0) WLGKM(6) MFMA8(af1, bf1)
  // tt = 63
  DSL(63, 1, af1, bf1) WLGKM(6) MFMA8(af0, bf0)
  WLGKM(0) MFMA8(af1, bf1)

  // Epilogue: dequant + store.
  // 32x32 C/D map: col = lane&31, row = (r&3) + 8*(r>>2) + 4*(lane>>5).
  const int rbase = lk * 4;
  float swv[2];
  #pragma unroll
  for (int fj = 0; fj < 2; ++fj) swv[fj] = sw[n0 + wn * 64 + fj * 32 + lr];
  #pragma unroll
  for (int fi = 0; fi < 4; ++fi) {
    #pragma unroll
    for (int r = 0; r < 16; ++r) {
      const int row = (r & 3) + 8 * (r >> 2) + rbase;
      const int grow = m0 + wm * 128 + fi * 32 + row;
      const float sxv = sx[grow];
      float* orow = out + (size_t)grow * N + n0 + wn * 64 + lr;
      #pragma unroll
      for (int fj = 0; fj < 2; ++fj) {
        orow[fj * 32] = (float)acc[fi][fj][r] * sxv * swv[fj];
      }
    }
  }
}

extern "C" void kernel_launch(void* const* d_in, const int* in_sizes, int n_in,
                              void* d_out, int out_size, void* d_ws, size_t ws_size,
                              hipStream_t stream) {
  const float* x = (const float*)d_in[0];
  const int* w32 = (const int*)d_in[1];
  const float* wscale = (const float*)d_in[2];
  float* out = (float*)d_out;

  signed char* xq = (signed char*)d_ws;
  signed char* wq = xq + (size_t)M * K;
  float* sx = (float*)(wq + (size_t)N * K);

  pack_w_kernel<<<(N * K / 4 + 255) / 256, 256, 0, stream>>>(w32, wq);
  quant_x_kernel<<<M, 256, 0, stream>>>(x, xq, sx);
  gemm_i8_kernel<<<NWG, 512, 131072, stream>>>(xq, wq, sx, wscale, out);
}